// Round 1
// baseline (1193.356 us; speedup 1.0000x reference)
//
#include <hip/hip_runtime.h>
#include <hip/hip_bf16.h>

// Problem: KMeans assign. x: (8,4096,512) f32 -> 32768 rows. centroids: (2048,512) f32.
// Outputs concatenated in d_out (float32): labels[32768] (as float values), assigned[32768*512].
// argmin_k ||(x+eps) - c_k||  ==  argmin_k ( ||c_k||^2 - 2*(x+eps).c_k )   (x_sq row-constant, sqrt monotone)

#define EPS 1e-6f

constexpr int BROWS = 32768;   // 8*4096
constexpr int DD    = 512;
constexpr int KC    = 2048;

constexpr int TM = 128;        // rows per block tile
constexpr int TN = 128;        // centroids per inner tile
constexpr int BK = 16;         // d-chunk
constexpr int CHUNK = 512;     // centroids per block (blockIdx.y chunk)
constexpr int XS = 132;        // padded LDS row stride (132*4B = 528 = 33*16B -> float4-aligned, breaks 32-bank aliasing)

// ---------------- kernel 0: c_sq[k] = sum_d centroids[k][d]^2 -------------
__global__ __launch_bounds__(256) void csq_kernel(const float* __restrict__ cen,
                                                  float* __restrict__ csq) {
    int wave = threadIdx.x >> 6;
    int lane = threadIdx.x & 63;
    int c = blockIdx.x * 4 + wave;           // grid 512 * 4 waves = 2048
    const float* row = cen + (size_t)c * DD;
    float4 v0 = *(const float4*)(row + lane * 8);
    float4 v1 = *(const float4*)(row + lane * 8 + 4);
    float s = v0.x*v0.x + v0.y*v0.y + v0.z*v0.z + v0.w*v0.w
            + v1.x*v1.x + v1.y*v1.y + v1.z*v1.z + v1.w*v1.w;
    #pragma unroll
    for (int off = 32; off > 0; off >>= 1) s += __shfl_down(s, off, 64);
    if (lane == 0) csq[c] = s;
}

// ---------------- kernel 1: partial argmin over a 512-centroid chunk ------
__global__ __launch_bounds__(256, 4) void dist_kernel(const float* __restrict__ x,
                                                      const float* __restrict__ cen,
                                                      const float* __restrict__ csq,
                                                      float* __restrict__ pval,
                                                      int*   __restrict__ pidx) {
    __shared__ float xs[BK][XS];
    __shared__ float cs[BK][XS];
    __shared__ float redv[TM][17];
    __shared__ int   redi[TM][17];

    const int tid = threadIdx.x;
    const int ty = tid >> 4;          // 0..15 -> row groups
    const int tx = tid & 15;          // 0..15 -> col groups
    const int rowBase = blockIdx.x * TM;
    const int colBase = blockIdx.y * CHUNK;

    float bestv[8];
    int   besti[8];
    #pragma unroll
    for (int i = 0; i < 8; i++) { bestv[i] = 3.4e38f; besti[i] = 0x7fffffff; }

    for (int ct = 0; ct < CHUNK; ct += TN) {
        const int cb = colBase + ct;
        float acc[8][8] = {};

        for (int dk = 0; dk < DD; dk += BK) {
            // ---- stage x tile (transposed, +eps) and c tile (transposed) ----
            #pragma unroll
            for (int s = 0; s < 2; s++) {
                int id = tid + s * 256;          // 0..511
                int r  = id >> 2;                // 0..127
                int dc = (id & 3) * 4;           // 0,4,8,12
                float4 xv = *(const float4*)(x + (size_t)(rowBase + r) * DD + dk + dc);
                xs[dc + 0][r] = xv.x + EPS;
                xs[dc + 1][r] = xv.y + EPS;
                xs[dc + 2][r] = xv.z + EPS;
                xs[dc + 3][r] = xv.w + EPS;
                float4 cv = *(const float4*)(cen + (size_t)(cb + r) * DD + dk + dc);
                cs[dc + 0][r] = cv.x;
                cs[dc + 1][r] = cv.y;
                cs[dc + 2][r] = cv.z;
                cs[dc + 3][r] = cv.w;
            }
            __syncthreads();

            // ---- 8x8 register tile FMA ----
            #pragma unroll
            for (int k = 0; k < BK; k++) {
                float4 a0 = *(const float4*)&xs[k][ty * 4];
                float4 a1 = *(const float4*)&xs[k][64 + ty * 4];
                float4 b0 = *(const float4*)&cs[k][tx * 4];
                float4 b1 = *(const float4*)&cs[k][64 + tx * 4];
                float a[8] = {a0.x, a0.y, a0.z, a0.w, a1.x, a1.y, a1.z, a1.w};
                float b[8] = {b0.x, b0.y, b0.z, b0.w, b1.x, b1.y, b1.z, b1.w};
                #pragma unroll
                for (int i = 0; i < 8; i++)
                    #pragma unroll
                    for (int j = 0; j < 8; j++)
                        acc[i][j] += a[i] * b[j];
            }
            __syncthreads();
        }

        // ---- fold this centroid tile into running per-row argmin ----
        #pragma unroll
        for (int j = 0; j < 8; j++) {
            int col = cb + ((j < 4) ? (tx * 4 + j) : (64 + tx * 4 + (j - 4)));
            float cq = csq[col];
            #pragma unroll
            for (int i = 0; i < 8; i++) {
                float v = cq - 2.0f * acc[i][j];
                if (v < bestv[i] || (v == bestv[i] && col < besti[i])) {
                    bestv[i] = v; besti[i] = col;
                }
            }
        }
    }

    // ---- cross-thread (tx) reduction per row via LDS ----
    #pragma unroll
    for (int i = 0; i < 8; i++) {
        int r = (i < 4) ? (ty * 4 + i) : (64 + ty * 4 + (i - 4));
        redv[r][tx] = bestv[i];
        redi[r][tx] = besti[i];
    }
    __syncthreads();

    if (tid < TM) {
        float bv = 3.4e38f; int bi = 0x7fffffff;
        #pragma unroll
        for (int t = 0; t < 16; t++) {
            float v = redv[tid][t]; int ix = redi[tid][t];
            if (v < bv || (v == bv && ix < bi)) { bv = v; bi = ix; }
        }
        int row = rowBase + tid;
        pval[(size_t)row * 4 + blockIdx.y] = bv;
        pidx[(size_t)row * 4 + blockIdx.y] = bi;
    }
}

// ---------------- kernel 2: final reduce + labels + centroid gather -------
__global__ __launch_bounds__(256) void finish_kernel(const float* __restrict__ cen,
                                                     const float* __restrict__ pval,
                                                     const int*   __restrict__ pidx,
                                                     float* __restrict__ out) {
    __shared__ int lab[8];
    const int tid = threadIdx.x;
    const int rowBase = blockIdx.x * 8;

    if (tid < 8) {
        int row = rowBase + tid;
        float bv = 3.4e38f; int bi = 0x7fffffff;
        #pragma unroll
        for (int c = 0; c < 4; c++) {
            float v = pval[(size_t)row * 4 + c];
            int  ix = pidx[(size_t)row * 4 + c];
            if (v < bv || (v == bv && ix < bi)) { bv = v; bi = ix; }
        }
        lab[tid] = bi;
        out[row] = (float)bi;               // labels stored as float32 values
    }
    __syncthreads();

    float* assigned = out + BROWS;
    #pragma unroll 4
    for (int s = tid; s < 8 * 128; s += 256) {   // 8 rows x 128 float4
        int r = s >> 7;
        int f = (s & 127) * 4;
        int lb = lab[r];
        float4 v = *(const float4*)(cen + (size_t)lb * DD + f);
        *(float4*)(assigned + (size_t)(rowBase + r) * DD + f) = v;
    }
}

extern "C" void kernel_launch(void* const* d_in, const int* in_sizes, int n_in,
                              void* d_out, int out_size, void* d_ws, size_t ws_size,
                              hipStream_t stream) {
    const float* x   = (const float*)d_in[0];
    const float* cen = (const float*)d_in[1];

    float* csq  = (float*)d_ws;                                    // 2048 f32 = 8 KB
    float* pval = (float*)((char*)d_ws + 8192);                    // 32768*4 f32 = 512 KB
    int*   pidx = (int*)  ((char*)d_ws + 8192 + (size_t)BROWS*4*4);// 32768*4 i32 = 512 KB

    csq_kernel<<<KC / 4, 256, 0, stream>>>(cen, csq);
    dist_kernel<<<dim3(BROWS / TM, KC / CHUNK), 256, 0, stream>>>(x, cen, csq, pval, pidx);
    finish_kernel<<<BROWS / 8, 256, 0, stream>>>(cen, pval, pidx, (float*)d_out);
}

// Round 2
// 916.285 us; speedup vs baseline: 1.3024x; 1.3024x over previous
//
#include <hip/hip_runtime.h>
#include <hip/hip_bf16.h>

// Problem: KMeans assign. x: (8,4096,512) f32 -> 32768 rows. centroids: (2048,512) f32.
// Outputs concatenated in d_out (float32): labels[32768] (as float values), assigned[32768*512].
// argmin_k ||(x+eps) - c_k||  ==  argmin_k ( ||c_k||^2 - 2*(x+eps).c_k )   (x_sq row-constant, sqrt monotone)

#define EPS 1e-6f

constexpr int BROWS = 32768;   // 8*4096
constexpr int DD    = 512;
constexpr int KC    = 2048;

constexpr int TM = 128;        // rows per block tile
constexpr int TN = 128;        // centroids per inner tile
constexpr int BK = 16;         // d-chunk
constexpr int CHUNK = 512;     // centroids per block (blockIdx.y chunk)
constexpr int XS = 132;        // padded LDS row stride (132*4B = 528 = 33*16B -> float4-aligned, breaks 32-bank aliasing)

// ---------------- kernel 0: c_sq[k] = sum_d centroids[k][d]^2 -------------
__global__ __launch_bounds__(256) void csq_kernel(const float* __restrict__ cen,
                                                  float* __restrict__ csq) {
    int wave = threadIdx.x >> 6;
    int lane = threadIdx.x & 63;
    int c = blockIdx.x * 4 + wave;           // grid 512 * 4 waves = 2048
    const float* row = cen + (size_t)c * DD;
    float4 v0 = *(const float4*)(row + lane * 8);
    float4 v1 = *(const float4*)(row + lane * 8 + 4);
    float s = v0.x*v0.x + v0.y*v0.y + v0.z*v0.z + v0.w*v0.w
            + v1.x*v1.x + v1.y*v1.y + v1.z*v1.z + v1.w*v1.w;
    #pragma unroll
    for (int off = 32; off > 0; off >>= 1) s += __shfl_down(s, off, 64);
    if (lane == 0) csq[c] = s;
}

// ---------------- kernel 1: partial argmin over a 512-centroid chunk ------
// launch_bounds(256, 2): allow up to 256 VGPRs/wave. R1's (256,4) capped the
// allocator at 64 VGPRs -> ~30-reg spill -> 1.5 GB of scratch HBM traffic.
__global__ __launch_bounds__(256, 2) void dist_kernel(const float* __restrict__ x,
                                                      const float* __restrict__ cen,
                                                      const float* __restrict__ csq,
                                                      float* __restrict__ pval,
                                                      int*   __restrict__ pidx) {
    __shared__ float xs[BK][XS];
    __shared__ float cs[BK][XS];
    __shared__ float redv[TM][17];
    __shared__ int   redi[TM][17];

    const int tid = threadIdx.x;
    const int ty = tid >> 4;          // 0..15 -> row groups
    const int tx = tid & 15;          // 0..15 -> col groups
    const int rowBase = blockIdx.x * TM;
    const int colBase = blockIdx.y * CHUNK;

    float bestv[8];
    int   besti[8];
    #pragma unroll
    for (int i = 0; i < 8; i++) { bestv[i] = 3.4e38f; besti[i] = 0x7fffffff; }

    for (int ct = 0; ct < CHUNK; ct += TN) {
        const int cb = colBase + ct;
        float acc[8][8] = {};

        for (int dk = 0; dk < DD; dk += BK) {
            // ---- stage x tile (transposed, +eps) and c tile (transposed) ----
            #pragma unroll
            for (int s = 0; s < 2; s++) {
                int id = tid + s * 256;          // 0..511
                int r  = id >> 2;                // 0..127
                int dc = (id & 3) * 4;           // 0,4,8,12
                float4 xv = *(const float4*)(x + (size_t)(rowBase + r) * DD + dk + dc);
                xs[dc + 0][r] = xv.x + EPS;
                xs[dc + 1][r] = xv.y + EPS;
                xs[dc + 2][r] = xv.z + EPS;
                xs[dc + 3][r] = xv.w + EPS;
                float4 cv = *(const float4*)(cen + (size_t)(cb + r) * DD + dk + dc);
                cs[dc + 0][r] = cv.x;
                cs[dc + 1][r] = cv.y;
                cs[dc + 2][r] = cv.z;
                cs[dc + 3][r] = cv.w;
            }
            __syncthreads();

            // ---- 8x8 register tile FMA ----
            #pragma unroll
            for (int k = 0; k < BK; k++) {
                float4 a0 = *(const float4*)&xs[k][ty * 4];
                float4 a1 = *(const float4*)&xs[k][64 + ty * 4];
                float4 b0 = *(const float4*)&cs[k][tx * 4];
                float4 b1 = *(const float4*)&cs[k][64 + tx * 4];
                float a[8] = {a0.x, a0.y, a0.z, a0.w, a1.x, a1.y, a1.z, a1.w};
                float b[8] = {b0.x, b0.y, b0.z, b0.w, b1.x, b1.y, b1.z, b1.w};
                #pragma unroll
                for (int i = 0; i < 8; i++)
                    #pragma unroll
                    for (int j = 0; j < 8; j++)
                        acc[i][j] += a[i] * b[j];
            }
            __syncthreads();
        }

        // ---- fold this centroid tile into running per-row argmin ----
        #pragma unroll
        for (int j = 0; j < 8; j++) {
            int col = cb + ((j < 4) ? (tx * 4 + j) : (64 + tx * 4 + (j - 4)));
            float cq = csq[col];
            #pragma unroll
            for (int i = 0; i < 8; i++) {
                float v = cq - 2.0f * acc[i][j];
                if (v < bestv[i] || (v == bestv[i] && col < besti[i])) {
                    bestv[i] = v; besti[i] = col;
                }
            }
        }
    }

    // ---- cross-thread (tx) reduction per row via LDS ----
    #pragma unroll
    for (int i = 0; i < 8; i++) {
        int r = (i < 4) ? (ty * 4 + i) : (64 + ty * 4 + (i - 4));
        redv[r][tx] = bestv[i];
        redi[r][tx] = besti[i];
    }
    __syncthreads();

    if (tid < TM) {
        float bv = 3.4e38f; int bi = 0x7fffffff;
        #pragma unroll
        for (int t = 0; t < 16; t++) {
            float v = redv[tid][t]; int ix = redi[tid][t];
            if (v < bv || (v == bv && ix < bi)) { bv = v; bi = ix; }
        }
        int row = rowBase + tid;
        pval[(size_t)row * 4 + blockIdx.y] = bv;
        pidx[(size_t)row * 4 + blockIdx.y] = bi;
    }
}

// ---------------- kernel 2: final reduce + labels + centroid gather -------
__global__ __launch_bounds__(256) void finish_kernel(const float* __restrict__ cen,
                                                     const float* __restrict__ pval,
                                                     const int*   __restrict__ pidx,
                                                     float* __restrict__ out) {
    __shared__ int lab[8];
    const int tid = threadIdx.x;
    const int rowBase = blockIdx.x * 8;

    if (tid < 8) {
        int row = rowBase + tid;
        float bv = 3.4e38f; int bi = 0x7fffffff;
        #pragma unroll
        for (int c = 0; c < 4; c++) {
            float v = pval[(size_t)row * 4 + c];
            int  ix = pidx[(size_t)row * 4 + c];
            if (v < bv || (v == bv && ix < bi)) { bv = v; bi = ix; }
        }
        lab[tid] = bi;
        out[row] = (float)bi;               // labels stored as float32 values
    }
    __syncthreads();

    float* assigned = out + BROWS;
    #pragma unroll 4
    for (int s = tid; s < 8 * 128; s += 256) {   // 8 rows x 128 float4
        int r = s >> 7;
        int f = (s & 127) * 4;
        int lb = lab[r];
        float4 v = *(const float4*)(cen + (size_t)lb * DD + f);
        *(float4*)(assigned + (size_t)(rowBase + r) * DD + f) = v;
    }
}

extern "C" void kernel_launch(void* const* d_in, const int* in_sizes, int n_in,
                              void* d_out, int out_size, void* d_ws, size_t ws_size,
                              hipStream_t stream) {
    const float* x   = (const float*)d_in[0];
    const float* cen = (const float*)d_in[1];

    float* csq  = (float*)d_ws;                                    // 2048 f32 = 8 KB
    float* pval = (float*)((char*)d_ws + 8192);                    // 32768*4 f32 = 512 KB
    int*   pidx = (int*)  ((char*)d_ws + 8192 + (size_t)BROWS*4*4);// 32768*4 i32 = 512 KB

    csq_kernel<<<KC / 4, 256, 0, stream>>>(cen, csq);
    dist_kernel<<<dim3(BROWS / TM, KC / CHUNK), 256, 0, stream>>>(x, cen, csq, pval, pidx);
    finish_kernel<<<BROWS / 8, 256, 0, stream>>>(cen, pval, pidx, (float*)d_out);
}

// Round 3
// 354.735 us; speedup vs baseline: 3.3641x; 2.5830x over previous
//
#include <hip/hip_runtime.h>
#include <hip/hip_bf16.h>

// KMeans assign via fp16 coarse MFMA + exact fp32 fixup of near-tie rows.
// argmin_k ||xe - c_k|| == argmin_k ( ||c_k||^2 - 2*xe.c_k ),  xe = x + 1e-6.
// Coarse fp16 dot error sigma ~0.016 (sq-dist units); rows with coarse
// top2 gap < TAU=0.3 (~13 sigma) are exactly rescored in fp32.

#define EPS 1e-6f
#define TAU 0.3f

constexpr int BROWS = 32768;   // 8*4096 rows
constexpr int DD    = 512;
constexpr int KC    = 2048;    // centroids
constexpr int FCAP  = 4096;    // max flagged rows handled exactly

typedef _Float16 half8  __attribute__((ext_vector_type(8)));
typedef _Float16 half4v __attribute__((ext_vector_type(4)));
typedef float    f32x4  __attribute__((ext_vector_type(4)));

// ---------------- prep: x -> fp16 (with eps) --------------------------------
__global__ __launch_bounds__(256) void prep_x(const float* __restrict__ x,
                                              _Float16* __restrict__ xh) {
    size_t i = ((size_t)blockIdx.x * 256 + threadIdx.x) * 4;
    float4 v = *(const float4*)(x + i);
    half4v h;
    h[0] = (_Float16)(v.x + EPS); h[1] = (_Float16)(v.y + EPS);
    h[2] = (_Float16)(v.z + EPS); h[3] = (_Float16)(v.w + EPS);
    *(half4v*)(xh + i) = h;
}

// ---------------- prep: centroids -> fp16, plus fp32 csq --------------------
__global__ __launch_bounds__(256) void prep_c(const float* __restrict__ cen,
                                              _Float16* __restrict__ ch,
                                              float* __restrict__ csq) {
    int w = threadIdx.x >> 6, lane = threadIdx.x & 63;
    int c = blockIdx.x * 4 + w;                    // grid 512 -> 2048 rows
    const float* row = cen + (size_t)c * DD;
    float4 v0 = *(const float4*)(row + lane * 8);
    float4 v1 = *(const float4*)(row + lane * 8 + 4);
    half8 h;
    h[0] = (_Float16)v0.x; h[1] = (_Float16)v0.y; h[2] = (_Float16)v0.z; h[3] = (_Float16)v0.w;
    h[4] = (_Float16)v1.x; h[5] = (_Float16)v1.y; h[6] = (_Float16)v1.z; h[7] = (_Float16)v1.w;
    *(half8*)(ch + (size_t)c * DD + lane * 8) = h;
    float s = v0.x*v0.x + v0.y*v0.y + v0.z*v0.z + v0.w*v0.w
            + v1.x*v1.x + v1.y*v1.y + v1.z*v1.z + v1.w*v1.w;
    #pragma unroll
    for (int off = 32; off > 0; off >>= 1) s += __shfl_down(s, off, 64);
    if (lane == 0) csq[c] = s;
}

// ---------------- coarse fp16 MFMA distance + per-row top2 ------------------
// 128x128 tile, 16x16x32_f16, global_load_lds width=16 staging (m97 shape).
__global__ __launch_bounds__(256) void dist_f16(const _Float16* __restrict__ xh,
                                                const _Float16* __restrict__ ch,
                                                const float* __restrict__ csq,
                                                float* __restrict__ pbest,
                                                float* __restrict__ psec,
                                                int*   __restrict__ pidx) {
    __shared__ __align__(16) _Float16 ash[128 * 32];
    __shared__ __align__(16) _Float16 bsh[128 * 32];

    const int tid = threadIdx.x;
    const int w = tid >> 6, lane = tid & 63;
    const int wr = w >> 1, wc = w & 1;
    const int quad = lane >> 4, u = lane & 15;
    const int rowBase = blockIdx.x * 128;
    const int colBase = blockIdx.y * 128;

    f32x4 acc[4][4] = {};

    for (int kc = 0; kc < DD / 32; kc++) {
        __syncthreads();
        #pragma unroll
        for (int i = 0; i < 2; i++) {
            int g = 128 * w + 64 * i + lane;       // granule 0..511 (16B each)
            int r = g >> 2, hh = g & 3;
            const _Float16* gA = xh + (size_t)(rowBase + r) * DD + kc * 32 + hh * 8;
            const _Float16* gB = ch + (size_t)(colBase + r) * DD + kc * 32 + hh * 8;
            __builtin_amdgcn_global_load_lds(
                (const __attribute__((address_space(1))) void*)gA,
                (__attribute__((address_space(3))) void*)(ash + g * 8), 16, 0, 0);
            __builtin_amdgcn_global_load_lds(
                (const __attribute__((address_space(1))) void*)gB,
                (__attribute__((address_space(3))) void*)(bsh + g * 8), 16, 0, 0);
        }
        __syncthreads();

        half8 af[4], bf[4];
        #pragma unroll
        for (int f = 0; f < 4; f++) {
            af[f] = *(const half8*)(ash + (wr * 64 + f * 16 + u) * 32 + quad * 8);
            bf[f] = *(const half8*)(bsh + (wc * 64 + f * 16 + u) * 32 + quad * 8);
        }
        #pragma unroll
        for (int fr = 0; fr < 4; fr++)
            #pragma unroll
            for (int fc = 0; fc < 4; fc++)
                acc[fr][fc] = __builtin_amdgcn_mfma_f32_16x16x32_f16(af[fr], bf[fc], acc[fr][fc], 0, 0, 0);
    }

    // epilogue: val = csq[col] - 2*dot; per-row top2 across 64 cols of this wave
    float cq[4];
    int   ci[4];
    #pragma unroll
    for (int fc = 0; fc < 4; fc++) {
        ci[fc] = colBase + wc * 64 + fc * 16 + u;
        cq[fc] = csq[ci[fc]];
    }
    const int cbi = blockIdx.y * 2 + wc;

    #pragma unroll
    for (int fr = 0; fr < 4; fr++) {
        #pragma unroll
        for (int reg = 0; reg < 4; reg++) {
            float b = 3.4e38f, s = 3.4e38f; int bi = 0x7fffffff;
            #pragma unroll
            for (int fc = 0; fc < 4; fc++) {
                float v = cq[fc] - 2.0f * acc[fr][fc][reg];
                int c = ci[fc];
                if (v < b || (v == b && c < bi)) { s = b; b = v; bi = c; }
                else if (v < s) s = v;
            }
            #pragma unroll
            for (int m = 1; m < 16; m <<= 1) {   // butterfly within quad (16 lanes)
                float ob = __shfl_xor(b, m, 64);
                int  obi = __shfl_xor(bi, m, 64);
                float os = __shfl_xor(s, m, 64);
                if (ob < b || (ob == b && obi < bi)) {
                    s = fminf(fminf(b, s), os); b = ob; bi = obi;
                } else {
                    s = fminf(s, fminf(ob, os));
                }
            }
            if (u == 0) {
                int grow = rowBase + wr * 64 + fr * 16 + quad * 4 + reg;
                pbest[cbi * BROWS + grow] = b;
                psec [cbi * BROWS + grow] = s;
                pidx [cbi * BROWS + grow] = bi;
            }
        }
    }
}

// ---------------- merge 32 partials per row; flag near-ties -----------------
__global__ __launch_bounds__(256) void reduce_rows(const float* __restrict__ pbest,
                                                   const float* __restrict__ psec,
                                                   const int* __restrict__ pidx,
                                                   float* __restrict__ out,
                                                   int* __restrict__ labels,
                                                   int* __restrict__ rlist,
                                                   int* __restrict__ ctr) {
    int row = blockIdx.x * 256 + threadIdx.x;    // grid 128
    float b = 3.4e38f, s = 3.4e38f; int bi = 0x7fffffff;
    for (int p = 0; p < 32; p++) {
        float v  = pbest[p * BROWS + row];
        float sv = psec [p * BROWS + row];
        int   vi = pidx [p * BROWS + row];
        if (v < b || (v == b && vi < bi)) { s = fminf(sv, fminf(b, s)); b = v; bi = vi; }
        else                              { s = fminf(s, fminf(v, sv)); }
    }
    out[row] = (float)bi;
    labels[row] = bi;
    if (s - b < TAU) {
        int slot = atomicAdd(ctr, 1);
        if (slot < FCAP) rlist[slot] = row;
    }
}

// ---------------- exact fp32 rescore of flagged rows (R2 structure) ---------
__global__ __launch_bounds__(256, 2) void fixup_dist(const float* __restrict__ x,
                                                     const float* __restrict__ cen,
                                                     const float* __restrict__ csq,
                                                     const int* __restrict__ rlist,
                                                     const int* __restrict__ ctr,
                                                     float* __restrict__ fbest,
                                                     int*   __restrict__ fidx) {
    int n = min(*ctr, FCAP);
    int tilebase = blockIdx.y * 128;
    if (tilebase >= n) return;

    __shared__ float xs[16][132];
    __shared__ float cs[16][132];
    __shared__ float redv[128][17];
    __shared__ int   redi[128][17];
    __shared__ int   rows[128];

    const int tid = threadIdx.x;
    if (tid < 128) rows[tid] = rlist[tilebase + tid];
    __syncthreads();

    const int ty = tid >> 4, tx = tid & 15;
    const int colBase = blockIdx.x * 128;

    float acc[8][8] = {};
    for (int dk = 0; dk < DD; dk += 16) {
        #pragma unroll
        for (int sI = 0; sI < 2; sI++) {
            int id = tid + sI * 256;
            int r  = id >> 2;
            int dc = (id & 3) * 4;
            float4 xv = *(const float4*)(x + (size_t)rows[r] * DD + dk + dc);
            xs[dc + 0][r] = xv.x + EPS; xs[dc + 1][r] = xv.y + EPS;
            xs[dc + 2][r] = xv.z + EPS; xs[dc + 3][r] = xv.w + EPS;
            float4 cv = *(const float4*)(cen + (size_t)(colBase + r) * DD + dk + dc);
            cs[dc + 0][r] = cv.x; cs[dc + 1][r] = cv.y;
            cs[dc + 2][r] = cv.z; cs[dc + 3][r] = cv.w;
        }
        __syncthreads();
        #pragma unroll
        for (int k = 0; k < 16; k++) {
            float4 a0 = *(const float4*)&xs[k][ty * 4];
            float4 a1 = *(const float4*)&xs[k][64 + ty * 4];
            float4 b0 = *(const float4*)&cs[k][tx * 4];
            float4 b1 = *(const float4*)&cs[k][64 + tx * 4];
            float a[8] = {a0.x, a0.y, a0.z, a0.w, a1.x, a1.y, a1.z, a1.w};
            float b[8] = {b0.x, b0.y, b0.z, b0.w, b1.x, b1.y, b1.z, b1.w};
            #pragma unroll
            for (int i = 0; i < 8; i++)
                #pragma unroll
                for (int j = 0; j < 8; j++)
                    acc[i][j] += a[i] * b[j];
        }
        __syncthreads();
    }

    float bv[8]; int bix[8];
    #pragma unroll
    for (int i = 0; i < 8; i++) { bv[i] = 3.4e38f; bix[i] = 0x7fffffff; }
    #pragma unroll
    for (int j = 0; j < 8; j++) {
        int col = colBase + ((j < 4) ? (tx * 4 + j) : (64 + tx * 4 + (j - 4)));
        float cq = csq[col];
        #pragma unroll
        for (int i = 0; i < 8; i++) {
            float v = cq - 2.0f * acc[i][j];
            if (v < bv[i] || (v == bv[i] && col < bix[i])) { bv[i] = v; bix[i] = col; }
        }
    }
    #pragma unroll
    for (int i = 0; i < 8; i++) {
        int r = (i < 4) ? (ty * 4 + i) : (64 + ty * 4 + (i - 4));
        redv[r][tx] = bv[i]; redi[r][tx] = bix[i];
    }
    __syncthreads();
    if (tid < 128) {
        float b = 3.4e38f; int bi = 0x7fffffff;
        #pragma unroll
        for (int t = 0; t < 16; t++) {
            float v = redv[tid][t]; int ix = redi[tid][t];
            if (v < b || (v == b && ix < bi)) { b = v; bi = ix; }
        }
        fbest[blockIdx.x * FCAP + tilebase + tid] = b;
        fidx [blockIdx.x * FCAP + tilebase + tid] = bi;
    }
}

__global__ __launch_bounds__(256) void fixup_reduce(const float* __restrict__ fbest,
                                                    const int* __restrict__ fidx,
                                                    const int* __restrict__ rlist,
                                                    const int* __restrict__ ctr,
                                                    float* __restrict__ out,
                                                    int* __restrict__ labels) {
    int s = blockIdx.x * 256 + threadIdx.x;      // grid 16
    int n = min(*ctr, FCAP);
    if (s >= n) return;
    float b = 3.4e38f; int bi = 0x7fffffff;
    for (int c = 0; c < 16; c++) {
        float v = fbest[c * FCAP + s]; int ix = fidx[c * FCAP + s];
        if (v < b || (v == b && ix < bi)) { b = v; bi = ix; }
    }
    int row = rlist[s];
    out[row] = (float)bi;
    labels[row] = bi;
}

// ---------------- gather assigned centroids ---------------------------------
__global__ __launch_bounds__(256) void gather(const float* __restrict__ cen,
                                              const int* __restrict__ labels,
                                              float* __restrict__ out) {
    __shared__ int lab[8];
    const int tid = threadIdx.x;
    const int rowBase = blockIdx.x * 8;
    if (tid < 8) lab[tid] = labels[rowBase + tid];
    __syncthreads();
    float* assigned = out + BROWS;
    #pragma unroll 4
    for (int s = tid; s < 8 * 128; s += 256) {
        int r = s >> 7;
        int f = (s & 127) * 4;
        float4 v = *(const float4*)(cen + (size_t)lab[r] * DD + f);
        *(float4*)(assigned + (size_t)(rowBase + r) * DD + f) = v;
    }
}

extern "C" void kernel_launch(void* const* d_in, const int* in_sizes, int n_in,
                              void* d_out, int out_size, void* d_ws, size_t ws_size,
                              hipStream_t stream) {
    const float* x   = (const float*)d_in[0];
    const float* cen = (const float*)d_in[1];

    char* base = (char*)d_ws;
    _Float16* xh   = (_Float16*)(base);                    // 32 MB
    _Float16* ch   = (_Float16*)(base + 33554432);         // 2 MB
    float* csq     = (float*)(base + 35651584);            // 8 KB
    float* pbest   = (float*)(base + 35659776);            // 4 MB
    float* psec    = (float*)(base + 39854080);            // 4 MB
    int*   pidx    = (int*)  (base + 44048384);            // 4 MB
    int*   labels  = (int*)  (base + 48242688);            // 128 KB
    int*   rlist   = (int*)  (base + 48373760);            // 16 KB
    float* fbest   = (float*)(base + 48390144);            // 256 KB
    int*   fidx    = (int*)  (base + 48652288);            // 256 KB
    int*   ctr     = (int*)  (base + 48914432);            // 4 B

    hipMemsetAsync(ctr, 0, 4, stream);
    hipMemsetAsync(rlist, 0, FCAP * 4, stream);

    prep_x<<<BROWS * DD / 4 / 256, 256, 0, stream>>>(x, xh);
    prep_c<<<KC / 4, 256, 0, stream>>>(cen, ch, csq);
    dist_f16<<<dim3(BROWS / 128, KC / 128), 256, 0, stream>>>(xh, ch, csq, pbest, psec, pidx);
    reduce_rows<<<BROWS / 256, 256, 0, stream>>>(pbest, psec, pidx, (float*)d_out, labels, rlist, ctr);
    fixup_dist<<<dim3(KC / 128, FCAP / 128), 256, 0, stream>>>(x, cen, csq, rlist, ctr, fbest, fidx);
    fixup_reduce<<<FCAP / 256, 256, 0, stream>>>(fbest, fidx, rlist, ctr, (float*)d_out, labels);
    gather<<<BROWS / 8, 256, 0, stream>>>(cen, labels, (float*)d_out);
}